// Round 2
// baseline (4533.578 us; speedup 1.0000x reference)
//
#include <hip/hip_runtime.h>
#include <cmath>

#define Wd 256
#define Hd 256
#define HWd 65536
#define NTOT 4194304
#define NPART 2048
#define LW 264                       // LDS row stride in floats (16B-aligned, +guards)

#define C_COUP (2.0f / 4194304.0f)   // 2*COUPLING/N
#define C_KIN  (0.2f / 4194304.0f)   // 2*ALPHA/N
#define C_VOID 0.0098f               // 2*GAMMA^2

struct Win6 { float w[6]; };

// window of 6 floats covering gx-1..gx+4 for a thread's 4 output cols,
// built from 3 aligned b128 reads (conflict-free: 16B lane stride)
__device__ __forceinline__ Win6 win(const float* p) {
    float4 A = *(const float4*)(p);
    float4 B = *(const float4*)(p + 4);
    float4 C = *(const float4*)(p + 8);
    Win6 r;
    r.w[0] = A.w; r.w[1] = B.x; r.w[2] = B.y; r.w[3] = B.z; r.w[4] = B.w; r.w[5] = C.x;
    return r;
}

// one field: load 12-row phi strip -> c1,c2 (corr with Sobel) -> dK (second corr), pv = center phi
__device__ __forceinline__ void field_pass(
        const float* __restrict__ phiIn, size_t base, int y0,
        int tid, int cg, int r0,
        float* sP, float* sC1, float* sC2,
        float dK[2][4], float pv[2][4])
{
#pragma unroll
    for (int k = 0; k < 3; ++k) {               // 12 rows x 64 float4
        int task = tid + k * 256;
        int row = task >> 6, c = task & 63;
        int gy = y0 - 2 + row;
        float4 v = make_float4(0.f, 0.f, 0.f, 0.f);
        if ((unsigned)gy < (unsigned)Hd)
            v = *(const float4*)(phiIn + base + (size_t)gy * Wd + 4 * c);
        *(float4*)&sP[row * LW + 4 + 4 * c] = v;
    }
    __syncthreads();
#pragma unroll
    for (int k = 0; k < 3; ++k) {               // c-stage: 10 rows x 64 groups
        int task = tid + k * 256;
        if (task < 640) {
            int row = task >> 6, c = task & 63;
            int gy = y0 - 1 + row;
            float c1v[4] = {0.f,0.f,0.f,0.f}, c2v[4] = {0.f,0.f,0.f,0.f};
            if ((unsigned)gy < (unsigned)Hd) {
                Win6 w0 = win(&sP[row * LW + 4 * c]);
                Win6 w1 = win(&sP[(row + 1) * LW + 4 * c]);
                Win6 w2 = win(&sP[(row + 2) * LW + 4 * c]);
#pragma unroll
                for (int j = 0; j < 4; ++j) {
                    c1v[j] = 0.125f * (w0.w[j+2] - w0.w[j]) + 0.25f * (w1.w[j+2] - w1.w[j]) + 0.125f * (w2.w[j+2] - w2.w[j]);
                    c2v[j] = 0.125f * (w2.w[j] - w0.w[j]) + 0.25f * (w2.w[j+1] - w0.w[j+1]) + 0.125f * (w2.w[j+2] - w0.w[j+2]);
                }
            }
            *(float4*)&sC1[row * LW + 4 + 4 * c] = make_float4(c1v[0], c1v[1], c1v[2], c1v[3]);
            *(float4*)&sC2[row * LW + 4 + 4 * c] = make_float4(c2v[0], c2v[1], c2v[2], c2v[3]);
        }
    }
    __syncthreads();
#pragma unroll
    for (int h = 0; h < 2; ++h) {               // d-stage: 2 output rows per thread
        int r = r0 + 4 * h;
        Win6 W0 = win(&sC1[r * LW + 4 * cg]);
        Win6 W1 = win(&sC1[(r + 1) * LW + 4 * cg]);
        Win6 W2 = win(&sC1[(r + 2) * LW + 4 * cg]);
        Win6 U0 = win(&sC2[r * LW + 4 * cg]);
        Win6 U2 = win(&sC2[(r + 2) * LW + 4 * cg]);
#pragma unroll
        for (int j = 0; j < 4; ++j) {
            dK[h][j] = 0.125f * (W0.w[j+2] - W0.w[j]) + 0.25f * (W1.w[j+2] - W1.w[j]) + 0.125f * (W2.w[j+2] - W2.w[j])
                     + 0.125f * (U2.w[j] - U0.w[j]) + 0.25f * (U2.w[j+1] - U0.w[j+1]) + 0.125f * (U2.w[j+2] - U0.w[j+2]);
        }
        float4 p4 = *(float4*)&sP[(r + 2) * LW + 4 + 4 * cg];
        pv[h][0] = p4.x; pv[h][1] = p4.y; pv[h][2] = p4.z; pv[h][3] = p4.w;
    }
    __syncthreads();
}

__global__ __launch_bounds__(256, 4)
void k_step(const float* __restrict__ S,
            const float* __restrict__ pxin, const float* __restrict__ pyin,
            float* __restrict__ pxout, float* __restrict__ pyout,
            float* __restrict__ mx, float* __restrict__ my,
            float* __restrict__ vx, float* __restrict__ vy,
            const float* __restrict__ partPrev, float* __restrict__ partCur,
            float a_step, float inv_bc2, int write_sp, float* __restrict__ sp)
{
    __shared__ float sP[12 * LW];
    __shared__ float sC1[10 * LW];
    __shared__ float sC2[10 * LW];
    __shared__ float sRed[8];

    const int tid = threadIdx.x;
    const int cg  = tid & 63;
    const int r0  = tid >> 6;
    const int y0  = blockIdx.x * 8;
    const size_t base = (size_t)blockIdx.y * HWd;

    // zero guard columns once (persist across both field passes)
    {
        int j = tid & 7;
        int col = (j < 4) ? j : 256 + j;
        if (tid < 96)        sP [((tid      ) >> 3) * LW + col] = 0.f;
        else if (tid < 176)  sC1[((tid -  96) >> 3) * LW + col] = 0.f;
        else                 sC2[((tid - 176) >> 3) * LW + col] = 0.f;
    }

    // prologue: per-wave redundant reduce of previous partials -> SSB coefs
    // (fixed order, identical on every wave/block -> deterministic)
    double ax = 0.0, ay = 0.0;
    for (int i = cg; i < NPART; i += 64) {
        ax += (double)partPrev[i];
        ay += (double)partPrev[NPART + i];
    }
#pragma unroll
    for (int off = 1; off < 64; off <<= 1) {
        ax += __shfl_xor(ax, off, 64);
        ay += __shfl_xor(ay, off, 64);
    }
    double nx = sqrt(ax), ny = sqrt(ay);
    double pn = nx + ny;
    double uu = pn * pn - 0.01;                  // V^2
    double sgn = (uu > 0.0) ? 1.0 : ((uu < 0.0) ? -1.0 : 0.0);
    const float coefx = (float)(0.2 * sgn * pn / nx);   // 2*BETA*sgn*(nx+ny)/nx
    const float coefy = (float)(0.2 * sgn * pn / ny);

    float dKx[2][4], dKy[2][4], pxa[2][4], pya[2][4];
    field_pass(pxin, base, y0, tid, cg, r0, sP, sC1, sC2, dKx, pxa);
    field_pass(pyin, base, y0, tid, cg, r0, sP, sC1, sC2, dKy, pya);

    float sumx = 0.f, sumy = 0.f;
#pragma unroll
    for (int h = 0; h < 2; ++h) {
        const int r = r0 + 4 * h;
        const int gy = y0 + r;
        const size_t idx = base + (size_t)gy * Wd + 4 * cg;
        float4 s4 = *(const float4*)(S + idx);
        float sa[4] = {s4.x, s4.y, s4.z, s4.w};
        float sE = (cg < 63) ? S[idx + 4] : 0.f;
        const bool okd = (gy + 1 < Hd);
        float4 sD = okd ? *(const float4*)(S + idx + Wd) : make_float4(0.f,0.f,0.f,0.f);
        float sdv[4] = {sD.x, sD.y, sD.z, sD.w};
        float4 m4x = *(const float4*)(mx + idx);
        float4 v4x = *(const float4*)(vx + idx);
        float4 m4y = *(const float4*)(my + idx);
        float4 v4y = *(const float4*)(vy + idx);
        float ma[4] = {m4x.x, m4x.y, m4x.z, m4x.w};
        float va[4] = {v4x.x, v4x.y, v4x.z, v4x.w};
        float mb[4] = {m4y.x, m4y.y, m4y.z, m4y.w};
        float vb[4] = {v4y.x, v4y.y, v4y.z, v4y.w};
        float nmx[4], nvx[4], npx[4], nmy[4], nvy[4], npy[4], spv[4];
#pragma unroll
        for (int j = 0; j < 4; ++j) {
            float dx_ = (j < 3) ? (sa[j + 1] - sa[j]) : ((cg < 63) ? (sE - sa[3]) : 0.f);
            float dy_ = okd ? (sdv[j] - sa[j]) : 0.f;
            float R = pxa[h][j] * dx_ + pya[h][j] * dy_;
            float vmc = (sa[j] < 0.05f) ? C_VOID : 0.f;
            float gx_ = C_COUP * R * dx_ - C_KIN * dKx[h][j] + (coefx + vmc) * pxa[h][j];
            float gy_ = C_COUP * R * dy_ - C_KIN * dKy[h][j] + (coefy + vmc) * pya[h][j];
            float m1 = 0.9f * ma[j] + 0.1f * gx_;
            float v1 = 0.999f * va[j] + 0.001f * gx_ * gx_;
            nmx[j] = m1; nvx[j] = v1;
            npx[j] = pxa[h][j] - a_step * m1 / (sqrtf(v1 * inv_bc2) + 1e-8f);
            sumx += npx[j] * npx[j];
            float m2 = 0.9f * mb[j] + 0.1f * gy_;
            float v2 = 0.999f * vb[j] + 0.001f * gy_ * gy_;
            nmy[j] = m2; nvy[j] = v2;
            npy[j] = pya[h][j] - a_step * m2 / (sqrtf(v2 * inv_bc2) + 1e-8f);
            sumy += npy[j] * npy[j];
            spv[j] = sa[j] + R;
        }
        *(float4*)(mx + idx)    = make_float4(nmx[0], nmx[1], nmx[2], nmx[3]);
        *(float4*)(vx + idx)    = make_float4(nvx[0], nvx[1], nvx[2], nvx[3]);
        *(float4*)(pxout + idx) = make_float4(npx[0], npx[1], npx[2], npx[3]);
        *(float4*)(my + idx)    = make_float4(nmy[0], nmy[1], nmy[2], nmy[3]);
        *(float4*)(vy + idx)    = make_float4(nvy[0], nvy[1], nvy[2], nvy[3]);
        *(float4*)(pyout + idx) = make_float4(npy[0], npy[1], npy[2], npy[3]);
        if (write_sp)
            *(float4*)(sp + idx) = make_float4(spv[0], spv[1], spv[2], spv[3]);
    }

    // block reduce -> partials (fixed order)
    for (int off = 32; off > 0; off >>= 1) {
        sumx += __shfl_down(sumx, off, 64);
        sumy += __shfl_down(sumy, off, 64);
    }
    if ((tid & 63) == 0) { sRed[r0] = sumx; sRed[4 + r0] = sumy; }
    __syncthreads();
    if (tid == 0) {
        int bid = blockIdx.y * 32 + blockIdx.x;
        partCur[bid]         = sRed[0] + sRed[1] + sRed[2] + sRed[3];
        partCur[NPART + bid] = sRed[4] + sRed[5] + sRed[6] + sRed[7];
    }
}

__global__ __launch_bounds__(256)
void k_init(const float* __restrict__ px0, const float* __restrict__ py0,
            float* __restrict__ pxA, float* __restrict__ pyA,
            float* __restrict__ mx, float* __restrict__ my,
            float* __restrict__ vx, float* __restrict__ vy,
            float* __restrict__ part0)
{
    __shared__ float sRed[8];
    const int tid = threadIdx.x;
    const size_t base = (size_t)blockIdx.x * 2048;
    float4 z4 = make_float4(0.f, 0.f, 0.f, 0.f);
    float sx = 0.f, sy = 0.f;
#pragma unroll
    for (int k = 0; k < 2; ++k) {
        size_t idx = base + (size_t)(k * 1024 + tid * 4);
        float4 x = *(const float4*)(px0 + idx);
        float4 y = *(const float4*)(py0 + idx);
        *(float4*)(pxA + idx) = x;  *(float4*)(pyA + idx) = y;
        *(float4*)(mx + idx) = z4;  *(float4*)(my + idx) = z4;
        *(float4*)(vx + idx) = z4;  *(float4*)(vy + idx) = z4;
        sx += x.x * x.x + x.y * x.y + x.z * x.z + x.w * x.w;
        sy += y.x * y.x + y.y * y.y + y.z * y.z + y.w * y.w;
    }
    for (int off = 32; off > 0; off >>= 1) {
        sx += __shfl_down(sx, off, 64);
        sy += __shfl_down(sy, off, 64);
    }
    if ((tid & 63) == 0) { sRed[tid >> 6] = sx; sRed[4 + (tid >> 6)] = sy; }
    __syncthreads();
    if (tid == 0) {
        part0[blockIdx.x]         = sRed[0] + sRed[1] + sRed[2] + sRed[3];
        part0[NPART + blockIdx.x] = sRed[4] + sRed[5] + sRed[6] + sRed[7];
    }
}

extern "C" void kernel_launch(void* const* d_in, const int* in_sizes, int n_in,
                              void* d_out, int out_size, void* d_ws, size_t ws_size,
                              hipStream_t stream) {
    (void)in_sizes; (void)n_in; (void)out_size; (void)ws_size;
    const float* S   = (const float*)d_in[0];
    const float* px0 = (const float*)d_in[1];
    const float* py0 = (const float*)d_in[2];
    float* out = (float*)d_out;

    float* sp     = out;                      // slot 0: Sp
    float* outA_x = out + (size_t)NTOT;       // slot 1: phi_x post
    float* outA_y = out + 2 * (size_t)NTOT;   // slot 2: phi_y post
    float* outB_x = out + 3 * (size_t)NTOT;   // slot 3: phi_x pre
    float* outB_y = out + 4 * (size_t)NTOT;   // slot 4: phi_y pre

    float* ws = (float*)d_ws;
    float* mx = ws;
    float* my = mx + (size_t)NTOT;
    float* vx = my + (size_t)NTOT;
    float* vy = vx + (size_t)NTOT;
    float* part0 = vy + (size_t)NTOT;         // 2*NPART floats each
    float* part1 = part0 + 2 * (size_t)NPART;
    float* part[2] = { part0, part1 };

    dim3 grid(32, 64), blk(256, 1, 1);

    k_init<<<NPART, 256, 0, stream>>>(px0, py0, outA_x, outA_y, mx, my, vx, vy, part0);

    for (int t = 1; t <= 50; ++t) {
        double bc1 = 1.0 - pow(0.9, (double)t);
        double bc2 = 1.0 - pow(0.999, (double)t);
        float a_step = (float)(0.05 / bc1);
        float inv_bc2 = (float)(1.0 / bc2);
        bool odd = (t & 1) != 0;
        const float* pix = odd ? outA_x : outB_x;
        const float* piy = odd ? outA_y : outB_y;
        float* pox = odd ? outB_x : outA_x;
        float* poy = odd ? outB_y : outA_y;
        const float* pprev = part[(t + 1) & 1];
        float* pcur = part[t & 1];
        k_step<<<grid, blk, 0, stream>>>(S, pix, piy, pox, poy,
                                         mx, my, vx, vy, pprev, pcur,
                                         a_step, inv_bc2, (t == 50) ? 1 : 0, sp);
    }
}